// Round 2
// baseline (360.061 us; speedup 1.0000x reference)
//
#include <hip/hip_runtime.h>
#include <math.h>

#define PHASE_BINS 100
#define EPSF 1e-10f
#define HW 262144           // 512*512
#define BATCH 64
#define BPB 64              // blocks per batch
#define CHUNK (HW / BPB)    // 4096 elements per block
#define THREADS 256

__device__ __forceinline__ float wave_reduce_sum(float v) {
    #pragma unroll
    for (int off = 32; off > 0; off >>= 1) v += __shfl_down(v, off, 64);
    return v;
}

// Branchless atan2 -> phase bin. Cephes-style reduction: r = min/max in [0,1],
// second reduction at tan(pi/8), degree-7 minimax poly (max err ~1e-7 rad).
// Misbinning only for samples within ~1e-7 rad of a bin edge -> O(1) samples
// in 33M -> KL delta ~1e-5, far under threshold.
__device__ __forceinline__ int phase_bin(float y, float x) {
    const float PI_F = 3.14159265358979323846f;
    float ax = fabsf(x), ay = fabsf(y);
    float mx = fmaxf(ax, ay), mn = fminf(ax, ay);
    float r  = mn * __builtin_amdgcn_rcpf(mx);          // [0,1], 1 ulp
    float rr = (r - 1.0f) * __builtin_amdgcn_rcpf(r + 1.0f); // (-0.293, 0]
    bool big = r > 0.4142135624f;
    float z = big ? rr : r;
    float s = z * z;
    float p = fmaf(fmaf(fmaf(8.05374449538e-2f, s, -1.38776856032e-1f), s,
                        1.99777106478e-1f), s, -3.33329491539e-1f);
    float th = fmaf(z * s, p, z);                       // atan(z)
    th += big ? 0.78539816340f : 0.0f;                  // + pi/4
    th = (ay > ax) ? 1.57079632679f - th : th;          // octant swap
    th = (x < 0.0f) ? PI_F - th : th;                   // quadrant
    th = (y < 0.0f) ? -th : th;                         // sign
    int bin = (int)((th + PI_F) * 15.9154943092f);      // *100/(2pi)
    return min(max(bin, 0), PHASE_BINS - 1);
}

// Pass 1: one read of A and B. Per batch accumulate:
//   SA = sum |A|, SB = sum |B|, T = sum |A|*ln(|A|/|B|)
// and 100-bin phase histograms of angle(A), angle(B).
__global__ __launch_bounds__(THREADS) void pass1_kernel(
    const float* __restrict__ A, const float* __restrict__ B,
    float* __restrict__ SA, float* __restrict__ SB, float* __restrict__ Tacc,
    unsigned int* __restrict__ histA, unsigned int* __restrict__ histB)
{
    // [hist][wave][lane-stripe][bin] : 2*4*2*100 = 1600 words = 6.4 KB
    __shared__ unsigned int h[2][4][2][PHASE_BINS];
    const int wave = threadIdx.x >> 6;
    const int lane = threadIdx.x & 63;

    for (int i = threadIdx.x; i < 2 * 4 * 2 * PHASE_BINS; i += THREADS)
        ((unsigned int*)h)[i] = 0u;
    __syncthreads();

    unsigned int* __restrict__ hA = &h[0][wave][lane & 1][0];
    unsigned int* __restrict__ hB = &h[1][wave][lane & 1][0];

    const int b   = blockIdx.x / BPB;
    const int blk = blockIdx.x % BPB;
    const size_t base = (size_t)b * (2 * HW);
    const float* Ar = A + base;
    const float* Ai = Ar + HW;
    const float* Br = B + base;
    const float* Bi = Br + HW;
    const int start = blk * CHUNK;

    float sA = 0.f, sB = 0.f, t = 0.f;

    for (int i = threadIdx.x * 4; i < CHUNK; i += THREADS * 4) {
        const int idx = start + i;
        float4 ar4 = *(const float4*)(Ar + idx);
        float4 ai4 = *(const float4*)(Ai + idx);
        float4 br4 = *(const float4*)(Br + idx);
        float4 bi4 = *(const float4*)(Bi + idx);
        const float* arp = (const float*)&ar4;
        const float* aip = (const float*)&ai4;
        const float* brp = (const float*)&br4;
        const float* bip = (const float*)&bi4;
        #pragma unroll
        for (int j = 0; j < 4; ++j) {
            float arj = arp[j], aij = aip[j];
            float brj = brp[j], bij = bip[j];
            float ra2 = fmaf(arj, arj, aij * aij);
            float rb2 = fmaf(brj, brj, bij * bij);
            float aa = __builtin_amdgcn_sqrtf(ra2);     // 1 ulp, fine for sums
            float bb = __builtin_amdgcn_sqrtf(rb2);
            sA += aa;
            sB += bb;
            // aa*(ln aa - ln bb) = aa * 0.5*ln2 * log2(ra2/rb2); clamp keeps
            // the degenerate (prob-0) ra2==0 / rb2==0 cases finite.
            float q = ra2 * __builtin_amdgcn_rcpf(rb2);
            q = fminf(fmaxf(q, 1e-37f), 1e37f);
            t = fmaf(aa * 0.34657359028f, __log2f(q), t);
            atomicAdd(hA + phase_bin(aij, arj), 1u);
            atomicAdd(hB + phase_bin(bij, brj), 1u);
        }
    }

    // reduce the three float sums per wave, one global atomic per wave
    sA = wave_reduce_sum(sA);
    sB = wave_reduce_sum(sB);
    t  = wave_reduce_sum(t);
    if (lane == 0) {
        atomicAdd(&SA[b], sA);
        atomicAdd(&SB[b], sB);
        atomicAdd(&Tacc[b], t);
    }

    __syncthreads();
    // merge the 8 per-(wave,stripe) histograms, one global atomic per bin
    if (threadIdx.x < 2 * PHASE_BINS) {
        int hi  = threadIdx.x / PHASE_BINS;
        int bin = threadIdx.x % PHASE_BINS;
        unsigned v = 0;
        #pragma unroll
        for (int w = 0; w < 4; ++w)
            v += h[hi][w][0][bin] + h[hi][w][1][bin];
        unsigned int* dst = hi ? histB : histA;
        atomicAdd(&dst[b * PHASE_BINS + bin], v);
    }
}

// Pass 2: tiny finalize. One block; wave w handles batches w, w+4, ...
__global__ __launch_bounds__(256) void pass2_kernel(
    const float* __restrict__ SA, const float* __restrict__ SB,
    const float* __restrict__ T,
    const unsigned int* __restrict__ histA, const unsigned int* __restrict__ histB,
    float* __restrict__ out)
{
    __shared__ float amp_sh[BATCH];
    __shared__ float wave_phase[4];
    const int wave = threadIdx.x >> 6;
    const int lane = threadIdx.x & 63;
    const float PI_F = 3.14159265358979323846f;
    const float step = (2.0f * PI_F) / PHASE_BINS;

    float local_phase = 0.f;
    for (int b = wave; b < BATCH; b += 4) {
        float d_a[2], d_b[2];
        float sum_a = 0.f, sum_b = 0.f;
        #pragma unroll
        for (int r = 0; r < 2; ++r) {
            int bin = lane + r * 64;
            float da = 0.f, db = 0.f;
            if (bin < PHASE_BINS) {
                float e0 = -PI_F + bin * step;
                float e1 = (bin == PHASE_BINS - 1) ? PI_F : (-PI_F + (bin + 1) * step);
                float w = e1 - e0;                       // fp32 edge widths (torch density)
                float denom = (float)HW * w;
                da = (float)histA[b * PHASE_BINS + bin] / denom;
                db = (float)histB[b * PHASE_BINS + bin] / denom;
            }
            d_a[r] = da; d_b[r] = db;
            sum_a += da; sum_b += db;
        }
        #pragma unroll
        for (int off = 32; off > 0; off >>= 1) {
            sum_a += __shfl_xor(sum_a, off, 64);
            sum_b += __shfl_xor(sum_b, off, 64);
        }
        float kl = 0.f;
        #pragma unroll
        for (int r = 0; r < 2; ++r) {
            int bin = lane + r * 64;
            if (bin < PHASE_BINS) {
                float p = d_a[r] / (sum_a + EPSF);
                float q = d_b[r] / (sum_b + EPSF);
                kl += p * logf((p + EPSF) / (q + EPSF));
            }
        }
        #pragma unroll
        for (int off = 32; off > 0; off >>= 1) kl += __shfl_xor(kl, off, 64);
        if (lane == 0) {
            local_phase += kl;
            float sa_raw = SA[b];
            float sa = sa_raw + EPSF;
            float sb = SB[b] + EPSF;
            amp_sh[b] = T[b] / sa + (sa_raw / sa) * logf(sb / sa);
        }
    }
    if (lane == 0) wave_phase[wave] = local_phase;
    __syncthreads();
    float phase_total = wave_phase[0] + wave_phase[1] + wave_phase[2] + wave_phase[3];
    if (threadIdx.x < BATCH)
        out[threadIdx.x] = 0.5f * amp_sh[threadIdx.x] + 0.5f * phase_total;
}

extern "C" void kernel_launch(void* const* d_in, const int* in_sizes, int n_in,
                              void* d_out, int out_size, void* d_ws, size_t ws_size,
                              hipStream_t stream) {
    const float* A = (const float*)d_in[0];
    const float* B = (const float*)d_in[1];
    float* out = (float*)d_out;

    float* SA = (float*)d_ws;
    float* SB = SA + BATCH;
    float* T  = SB + BATCH;
    unsigned int* histA = (unsigned int*)(T + BATCH);
    unsigned int* histB = histA + BATCH * PHASE_BINS;

    size_t zero_bytes = (size_t)(3 * BATCH) * sizeof(float)
                      + (size_t)(2 * BATCH * PHASE_BINS) * sizeof(unsigned int);
    hipMemsetAsync(d_ws, 0, zero_bytes, stream);

    pass1_kernel<<<dim3(BATCH * BPB), dim3(THREADS), 0, stream>>>(
        A, B, SA, SB, T, histA, histB);
    pass2_kernel<<<1, 256, 0, stream>>>(SA, SB, T, histA, histB, out);
}

// Round 3
// 300.510 us; speedup vs baseline: 1.1982x; 1.1982x over previous
//
#include <hip/hip_runtime.h>
#include <math.h>

#define PHASE_BINS 100
#define EPSF 1e-10f
#define HW 262144           // 512*512
#define BATCH 64
#define BPB 32              // blocks per batch -> 2048 blocks = 8/CU, one round
#define CHUNK (HW / BPB)    // 8192 elements per block
#define THREADS 256
#define GROUPS (CHUNK / (THREADS * 4))   // 8 groups of 4 elements per thread

__device__ __forceinline__ float wave_reduce_sum(float v) {
    #pragma unroll
    for (int off = 32; off > 0; off >>= 1) v += __shfl_down(v, off, 64);
    return v;
}

// Branchless atan2 -> phase bin (cephes-style, max err ~1e-7 rad; verified
// absmax 0.0 in rounds 1-2 -- do not churn).
__device__ __forceinline__ int phase_bin(float y, float x) {
    const float PI_F = 3.14159265358979323846f;
    float ax = fabsf(x), ay = fabsf(y);
    float mx = fmaxf(ax, ay), mn = fminf(ax, ay);
    float r  = mn * __builtin_amdgcn_rcpf(mx);
    float rr = (r - 1.0f) * __builtin_amdgcn_rcpf(r + 1.0f);
    bool big = r > 0.4142135624f;
    float z = big ? rr : r;
    float s = z * z;
    float p = fmaf(fmaf(fmaf(8.05374449538e-2f, s, -1.38776856032e-1f), s,
                        1.99777106478e-1f), s, -3.33329491539e-1f);
    float th = fmaf(z * s, p, z);
    th += big ? 0.78539816340f : 0.0f;
    th = (ay > ax) ? 1.57079632679f - th : th;
    th = (x < 0.0f) ? PI_F - th : th;
    th = (y < 0.0f) ? -th : th;
    int bin = (int)((th + PI_F) * 15.9154943092f);
    return min(max(bin, 0), PHASE_BINS - 1);
}

__global__ __launch_bounds__(THREADS) void pass1_kernel(
    const float* __restrict__ A, const float* __restrict__ B,
    float* __restrict__ SA, float* __restrict__ SB, float* __restrict__ Tacc,
    unsigned int* __restrict__ histA, unsigned int* __restrict__ histB)
{
    __shared__ unsigned int h[2][4][PHASE_BINS];  // 800 words = 3.2 KB
    const int wave = threadIdx.x >> 6;
    const int lane = threadIdx.x & 63;

    for (int i = threadIdx.x; i < 2 * 4 * PHASE_BINS; i += THREADS)
        ((unsigned int*)h)[i] = 0u;
    __syncthreads();

    unsigned int* __restrict__ hA = &h[0][wave][0];
    unsigned int* __restrict__ hB = &h[1][wave][0];

    const int b   = blockIdx.x / BPB;
    const int blk = blockIdx.x % BPB;
    const size_t base = (size_t)b * (2 * HW);
    const float* Ar = A + base;
    const float* Ai = Ar + HW;
    const float* Br = B + base;
    const float* Bi = Br + HW;

    float sA = 0.f, sB = 0.f, t = 0.f;

    int idx = blk * CHUNK + threadIdx.x * 4;
    // prefetch group 0
    float4 car = *(const float4*)(Ar + idx);
    float4 cai = *(const float4*)(Ai + idx);
    float4 cbr = *(const float4*)(Br + idx);
    float4 cbi = *(const float4*)(Bi + idx);

    #pragma unroll 1
    for (int g = 0; g < GROUPS; ++g) {
        const int nidx = idx + THREADS * 4;
        float4 nar, nai, nbr, nbi;
        if (g + 1 < GROUPS) {          // issue next group's loads early
            nar = *(const float4*)(Ar + nidx);
            nai = *(const float4*)(Ai + nidx);
            nbr = *(const float4*)(Br + nidx);
            nbi = *(const float4*)(Bi + nidx);
        }
        const float* arp = (const float*)&car;
        const float* aip = (const float*)&cai;
        const float* brp = (const float*)&cbr;
        const float* bip = (const float*)&cbi;
        #pragma unroll
        for (int j = 0; j < 4; ++j) {
            float arj = arp[j], aij = aip[j];
            float brj = brp[j], bij = bip[j];
            float ra2 = fmaf(arj, arj, aij * aij);
            float rb2 = fmaf(brj, brj, bij * bij);
            float aa = __builtin_amdgcn_sqrtf(ra2);
            float bb = __builtin_amdgcn_sqrtf(rb2);
            sA += aa;
            sB += bb;
            float q = ra2 * __builtin_amdgcn_rcpf(rb2);
            q = fminf(fmaxf(q, 1e-37f), 1e37f);
            t = fmaf(aa * 0.34657359028f, __log2f(q), t);
            atomicAdd(hA + phase_bin(aij, arj), 1u);
            atomicAdd(hB + phase_bin(bij, brj), 1u);
        }
        car = nar; cai = nai; cbr = nbr; cbi = nbi;
        idx = nidx;
    }

    sA = wave_reduce_sum(sA);
    sB = wave_reduce_sum(sB);
    t  = wave_reduce_sum(t);
    if (lane == 0) {
        atomicAdd(&SA[b], sA);
        atomicAdd(&SB[b], sB);
        atomicAdd(&Tacc[b], t);
    }

    __syncthreads();
    if (threadIdx.x < 2 * PHASE_BINS) {
        int hi  = threadIdx.x / PHASE_BINS;
        int bin = threadIdx.x % PHASE_BINS;
        unsigned v = h[hi][0][bin] + h[hi][1][bin] + h[hi][2][bin] + h[hi][3][bin];
        unsigned int* dst = hi ? histB : histA;
        atomicAdd(&dst[b * PHASE_BINS + bin], v);
    }
}

// pass2a: one wave per batch. Densities (fp32 torch edge widths), normalize,
// phase KL -> atomicAdd into phase_total; amplitude loss -> amp[b].
__global__ __launch_bounds__(64) void pass2a_kernel(
    const float* __restrict__ SA, const float* __restrict__ SB,
    const float* __restrict__ T,
    const unsigned int* __restrict__ histA, const unsigned int* __restrict__ histB,
    float* __restrict__ amp, float* __restrict__ phase_total)
{
    const int b = blockIdx.x;
    const int lane = threadIdx.x;
    const float PI_F = 3.14159265358979323846f;
    const float step = (2.0f * PI_F) / PHASE_BINS;

    float d_a[2], d_b[2];
    float sum_a = 0.f, sum_b = 0.f;
    #pragma unroll
    for (int r = 0; r < 2; ++r) {
        int bin = lane + r * 64;
        float da = 0.f, db = 0.f;
        if (bin < PHASE_BINS) {
            float e0 = -PI_F + bin * step;
            float e1 = (bin == PHASE_BINS - 1) ? PI_F : (-PI_F + (bin + 1) * step);
            float w = e1 - e0;                       // fp32 edge widths (torch density)
            float denom = (float)HW * w;
            da = (float)histA[b * PHASE_BINS + bin] / denom;
            db = (float)histB[b * PHASE_BINS + bin] / denom;
        }
        d_a[r] = da; d_b[r] = db;
        sum_a += da; sum_b += db;
    }
    #pragma unroll
    for (int off = 32; off > 0; off >>= 1) {
        sum_a += __shfl_xor(sum_a, off, 64);
        sum_b += __shfl_xor(sum_b, off, 64);
    }
    float kl = 0.f;
    #pragma unroll
    for (int r = 0; r < 2; ++r) {
        int bin = lane + r * 64;
        if (bin < PHASE_BINS) {
            float p = d_a[r] / (sum_a + EPSF);
            float q = d_b[r] / (sum_b + EPSF);
            kl += p * logf((p + EPSF) / (q + EPSF));
        }
    }
    #pragma unroll
    for (int off = 32; off > 0; off >>= 1) kl += __shfl_xor(kl, off, 64);

    if (lane == 0) {
        atomicAdd(phase_total, kl);
        float sa_raw = SA[b];
        float sa = sa_raw + EPSF;
        float sb = SB[b] + EPSF;
        amp[b] = T[b] / sa + (sa_raw / sa) * logf(sb / sa);
    }
}

__global__ __launch_bounds__(64) void pass2b_kernel(
    const float* __restrict__ amp, const float* __restrict__ phase_total,
    float* __restrict__ out)
{
    int b = threadIdx.x;
    out[b] = 0.5f * amp[b] + 0.5f * phase_total[0];
}

extern "C" void kernel_launch(void* const* d_in, const int* in_sizes, int n_in,
                              void* d_out, int out_size, void* d_ws, size_t ws_size,
                              hipStream_t stream) {
    const float* A = (const float*)d_in[0];
    const float* B = (const float*)d_in[1];
    float* out = (float*)d_out;

    float* SA = (float*)d_ws;
    float* SB = SA + BATCH;
    float* T  = SB + BATCH;
    unsigned int* histA = (unsigned int*)(T + BATCH);
    unsigned int* histB = histA + BATCH * PHASE_BINS;
    float* phase_total = (float*)(histB + BATCH * PHASE_BINS);
    float* amp = phase_total + 1;

    // zero SA/SB/T, both histograms, and phase_total
    size_t zero_bytes = (size_t)(3 * BATCH) * sizeof(float)
                      + (size_t)(2 * BATCH * PHASE_BINS) * sizeof(unsigned int)
                      + sizeof(float);
    hipMemsetAsync(d_ws, 0, zero_bytes, stream);

    pass1_kernel<<<dim3(BATCH * BPB), dim3(THREADS), 0, stream>>>(
        A, B, SA, SB, T, histA, histB);
    pass2a_kernel<<<dim3(BATCH), dim3(64), 0, stream>>>(
        SA, SB, T, histA, histB, amp, phase_total);
    pass2b_kernel<<<1, 64, 0, stream>>>(amp, phase_total, out);
}

// Round 4
// 293.793 us; speedup vs baseline: 1.2256x; 1.0229x over previous
//
#include <hip/hip_runtime.h>
#include <math.h>

#define PHASE_BINS 100
#define EPSF 1e-10f
#define HW 262144           // 512*512
#define BATCH 64
#define BPB 32              // 2048 blocks = 8/CU, one round
#define CHUNK (HW / BPB)    // 8192 elements per block
#define THREADS 256
#define GROUPS (CHUNK / (THREADS * 4))   // 8 groups of 4 elements per thread

__device__ __forceinline__ float wave_reduce_sum(float v) {
    #pragma unroll
    for (int off = 32; off > 0; off >>= 1) v += __shfl_down(v, off, 64);
    return v;
}

// atan(z) for z in [0,1]: A&S 4.4.49 odd minimax poly, max err ~2e-8 rad.
__device__ __forceinline__ float atan01(float z) {
    float s = z * z;
    float p = fmaf(s, 0.0028662257f, -0.0161657367f);
    p = fmaf(s, p, 0.0429096138f);
    p = fmaf(s, p, -0.0752896400f);
    p = fmaf(s, p, 0.1065626393f);
    p = fmaf(s, p, -0.1420889944f);
    p = fmaf(s, p, 0.1999355085f);
    p = fmaf(s, p, -0.3333314528f);
    return fmaf(z * s, p, z);
}

// Branchless atan2 -> phase bin. One rcp + poly (err ~1e-7 rad total);
// verified absmax 0.0 with the coarser cephes variant in rounds 1-3.
__device__ __forceinline__ int phase_bin(float y, float x) {
    const float PI_F = 3.14159265358979323846f;
    float ax = fabsf(x), ay = fabsf(y);
    float mx = fmaxf(ax, ay), mn = fminf(ax, ay);
    float r  = mn * __builtin_amdgcn_rcpf(mx);
    float th = atan01(r);
    th = (ay > ax) ? 1.57079632679f - th : th;
    th = (x < 0.0f) ? PI_F - th : th;
    th = (y < 0.0f) ? -th : th;
    int bin = (int)((th + PI_F) * 15.9154943092f);   // *100/(2pi)
    return min(max(bin, 0), PHASE_BINS - 1);
}

#define PROC4(vAr, vAi, vBr, vBi)                                          \
    {                                                                       \
        const float* arp = (const float*)&vAr;                              \
        const float* aip = (const float*)&vAi;                              \
        const float* brp = (const float*)&vBr;                              \
        const float* bip = (const float*)&vBi;                              \
        _Pragma("unroll")                                                   \
        for (int j = 0; j < 4; ++j) {                                       \
            float arj = arp[j], aij = aip[j];                               \
            float brj = brp[j], bij = bip[j];                               \
            float ra2 = fmaf(arj, arj, aij * aij);                          \
            float rb2 = fmaf(brj, brj, bij * bij);                          \
            float aa = __builtin_amdgcn_sqrtf(ra2);                         \
            float bb = __builtin_amdgcn_sqrtf(rb2);                         \
            sA += aa;                                                       \
            sB += bb;                                                       \
            float la = __log2f(fmaxf(ra2, 1e-37f));                         \
            float lb = __log2f(fmaxf(rb2, 1e-37f));                         \
            t = fmaf(aa * 0.34657359028f, la - lb, t);                      \
            atomicAdd(hA + phase_bin(aij, arj), 1u);                        \
            atomicAdd(hB + phase_bin(bij, brj), 1u);                        \
        }                                                                   \
    }

__global__ __launch_bounds__(THREADS, 8) void pass1_kernel(
    const float* __restrict__ A, const float* __restrict__ B,
    float* __restrict__ SA, float* __restrict__ SB, float* __restrict__ Tacc,
    unsigned int* __restrict__ histA, unsigned int* __restrict__ histB)
{
    __shared__ unsigned int h[2][4][PHASE_BINS];  // 800 words = 3.2 KB
    const int wave = threadIdx.x >> 6;
    const int lane = threadIdx.x & 63;

    for (int i = threadIdx.x; i < 2 * 4 * PHASE_BINS; i += THREADS)
        ((unsigned int*)h)[i] = 0u;
    __syncthreads();

    unsigned int* __restrict__ hA = &h[0][wave][0];
    unsigned int* __restrict__ hB = &h[1][wave][0];

    const int b   = blockIdx.x / BPB;
    const int blk = blockIdx.x % BPB;
    const size_t base = (size_t)b * (2 * HW);
    const float* Ar = A + base;
    const float* Ai = Ar + HW;
    const float* Br = B + base;
    const float* Bi = Br + HW;

    float sA = 0.f, sB = 0.f, t = 0.f;

    int idx = blk * CHUNK + threadIdx.x * 4;
    // stage 0
    float4 cAr = *(const float4*)(Ar + idx);
    float4 cAi = *(const float4*)(Ai + idx);
    float4 cBr = *(const float4*)(Br + idx);
    float4 cBi = *(const float4*)(Bi + idx);

    #pragma unroll 1
    for (int g = 0; g < GROUPS - 1; ++g) {
        idx += THREADS * 4;
        // issue next group's loads, then fence so they stay ABOVE the compute
        float4 nAr = *(const float4*)(Ar + idx);
        float4 nAi = *(const float4*)(Ai + idx);
        float4 nBr = *(const float4*)(Br + idx);
        float4 nBi = *(const float4*)(Bi + idx);
        __builtin_amdgcn_sched_barrier(0);
        PROC4(cAr, cAi, cBr, cBi);
        cAr = nAr; cAi = nAi; cBr = nBr; cBi = nBi;
    }
    PROC4(cAr, cAi, cBr, cBi);   // peeled last group

    sA = wave_reduce_sum(sA);
    sB = wave_reduce_sum(sB);
    t  = wave_reduce_sum(t);
    if (lane == 0) {
        atomicAdd(&SA[b], sA);
        atomicAdd(&SB[b], sB);
        atomicAdd(&Tacc[b], t);
    }

    __syncthreads();
    if (threadIdx.x < 2 * PHASE_BINS) {
        int hi  = threadIdx.x / PHASE_BINS;
        int bin = threadIdx.x % PHASE_BINS;
        unsigned v = h[hi][0][bin] + h[hi][1][bin] + h[hi][2][bin] + h[hi][3][bin];
        unsigned int* dst = hi ? histB : histA;
        atomicAdd(&dst[b * PHASE_BINS + bin], v);
    }
}

// pass2a: one wave per batch. Densities (fp32 torch edge widths), normalize,
// phase KL -> atomicAdd into phase_total; amplitude loss -> amp[b].
__global__ __launch_bounds__(64) void pass2a_kernel(
    const float* __restrict__ SA, const float* __restrict__ SB,
    const float* __restrict__ T,
    const unsigned int* __restrict__ histA, const unsigned int* __restrict__ histB,
    float* __restrict__ amp, float* __restrict__ phase_total)
{
    const int b = blockIdx.x;
    const int lane = threadIdx.x;
    const float PI_F = 3.14159265358979323846f;
    const float step = (2.0f * PI_F) / PHASE_BINS;

    float d_a[2], d_b[2];
    float sum_a = 0.f, sum_b = 0.f;
    #pragma unroll
    for (int r = 0; r < 2; ++r) {
        int bin = lane + r * 64;
        float da = 0.f, db = 0.f;
        if (bin < PHASE_BINS) {
            float e0 = -PI_F + bin * step;
            float e1 = (bin == PHASE_BINS - 1) ? PI_F : (-PI_F + (bin + 1) * step);
            float w = e1 - e0;                       // fp32 edge widths (torch density)
            float denom = (float)HW * w;
            da = (float)histA[b * PHASE_BINS + bin] / denom;
            db = (float)histB[b * PHASE_BINS + bin] / denom;
        }
        d_a[r] = da; d_b[r] = db;
        sum_a += da; sum_b += db;
    }
    #pragma unroll
    for (int off = 32; off > 0; off >>= 1) {
        sum_a += __shfl_xor(sum_a, off, 64);
        sum_b += __shfl_xor(sum_b, off, 64);
    }
    float kl = 0.f;
    #pragma unroll
    for (int r = 0; r < 2; ++r) {
        int bin = lane + r * 64;
        if (bin < PHASE_BINS) {
            float p = d_a[r] / (sum_a + EPSF);
            float q = d_b[r] / (sum_b + EPSF);
            kl += p * logf((p + EPSF) / (q + EPSF));
        }
    }
    #pragma unroll
    for (int off = 32; off > 0; off >>= 1) kl += __shfl_xor(kl, off, 64);

    if (lane == 0) {
        atomicAdd(phase_total, kl);
        float sa_raw = SA[b];
        float sa = sa_raw + EPSF;
        float sb = SB[b] + EPSF;
        amp[b] = T[b] / sa + (sa_raw / sa) * logf(sb / sa);
    }
}

__global__ __launch_bounds__(64) void pass2b_kernel(
    const float* __restrict__ amp, const float* __restrict__ phase_total,
    float* __restrict__ out)
{
    int b = threadIdx.x;
    out[b] = 0.5f * amp[b] + 0.5f * phase_total[0];
}

extern "C" void kernel_launch(void* const* d_in, const int* in_sizes, int n_in,
                              void* d_out, int out_size, void* d_ws, size_t ws_size,
                              hipStream_t stream) {
    const float* A = (const float*)d_in[0];
    const float* B = (const float*)d_in[1];
    float* out = (float*)d_out;

    float* SA = (float*)d_ws;
    float* SB = SA + BATCH;
    float* T  = SB + BATCH;
    unsigned int* histA = (unsigned int*)(T + BATCH);
    unsigned int* histB = histA + BATCH * PHASE_BINS;
    float* phase_total = (float*)(histB + BATCH * PHASE_BINS);
    float* amp = phase_total + 1;

    // zero SA/SB/T, both histograms, and phase_total
    size_t zero_bytes = (size_t)(3 * BATCH) * sizeof(float)
                      + (size_t)(2 * BATCH * PHASE_BINS) * sizeof(unsigned int)
                      + sizeof(float);
    hipMemsetAsync(d_ws, 0, zero_bytes, stream);

    pass1_kernel<<<dim3(BATCH * BPB), dim3(THREADS), 0, stream>>>(
        A, B, SA, SB, T, histA, histB);
    pass2a_kernel<<<dim3(BATCH), dim3(64), 0, stream>>>(
        SA, SB, T, histA, histB, amp, phase_total);
    pass2b_kernel<<<1, 64, 0, stream>>>(amp, phase_total, out);
}